// Round 15
// baseline (167.188 us; speedup 1.0000x reference)
//
#include <hip/hip_runtime.h>
#include <hip/hip_bf16.h>

#define DD 256
#define NN 204800
#define SB 4096

typedef __attribute__((ext_vector_type(8))) short bf16x8;
typedef __attribute__((ext_vector_type(4))) float f32x4;

__device__ __forceinline__ unsigned short f2bf(float x) {
    union { float f; unsigned u; } v; v.f = x;
    unsigned r = v.u + 0x7FFF + ((v.u >> 16) & 1);
    return (unsigned short)(r >> 16);
}
__device__ __forceinline__ float bf2f(unsigned short h) {
    union { unsigned u; float f; } v; v.u = ((unsigned)h) << 16;
    return v.f;
}

// ---- K1: segstart (blk 0..16) | pack Wu->bf16 frag order (17..272) |
//          transpose Wv (273..336) --------------------------------------------
// pack: o = ((dt*8+kt)*64 + kg*16 + colr)*8 + j <- Wu[(dt*16+colr)][kt*32+kg*8+j]
__global__ void k_prep(const int* __restrict__ seg, const float* __restrict__ Wu,
                       const float* __restrict__ Wv,
                       int* __restrict__ seg_start, unsigned short* __restrict__ wub,
                       float* __restrict__ wvT) {
    int blk = blockIdx.x, t = threadIdx.x;
    if (blk < 17) {
        int b = blk * 256 + t;
        if (b > SB) return;
        int lo = 0, hi = NN;
        while (lo < hi) {
            int mid = (lo + hi) >> 1;
            if (seg[mid] < b) lo = mid + 1; else hi = mid;
        }
        seg_start[b] = lo;
    } else if (blk < 273) {
        int o = (blk - 17) * 256 + t;        // 65536 total
        int j    = o & 7;
        int colr = (o >> 3) & 15;
        int kg   = (o >> 7) & 3;
        int kt   = (o >> 9) & 7;
        int dt   = o >> 12;
        wub[o] = f2bf(Wu[(dt * 16 + colr) * DD + kt * 32 + kg * 8 + j]);
    } else {
        // transpose Wv: wvT[k][d] = Wv[d][k]; 64 blocks x 256 threads x 4 elems
        int idx = (blk - 273) * 1024 + t * 4;
        int d = idx >> 8, k0 = idx & 255;
        const float4 v = *(const float4*)&Wv[d * DD + k0];
        wvT[(size_t)(k0 + 0) * DD + d] = v.x;
        wvT[(size_t)(k0 + 1) * DD + d] = v.y;
        wvT[(size_t)(k0 + 2) * DD + d] = v.z;
        wvT[(size_t)(k0 + 3) * DD + d] = v.w;
    }
}

// ---- K2: anchor = segment mean (f32) + bf16 mirror + fused feat_v ------------
// Streaming phase unchanged (nt f32 loads, bf16 mirror). Epilogue: anchor into
// LDS, then fv[d] = bv[d] + sum_k anc[k]*wvT[k][d] with coalesced L2-hot
// column-slab loads — removes the separate k_featv launch entirely.
__global__ __launch_bounds__(256) void k_anchor(
    const float* __restrict__ ifeat, const int* __restrict__ seg_start,
    const float* __restrict__ wvT, const float* __restrict__ bv,
    unsigned short* __restrict__ xbf, float* __restrict__ feat_v,
    float* __restrict__ out)
{
    __shared__ float ancp[4][DD];
    __shared__ float anc_s[DD];
    int b = blockIdx.x, t = threadIdx.x;
    int rg = t >> 6, ct = (t & 63) * 4;
    int s0 = seg_start[b], s1 = seg_start[b + 1];
    int C = s1 - s0;
    f32x4 asum = {0.f, 0.f, 0.f, 0.f};
    for (int i0 = 0; i0 < C; i0 += 4) {
        int i = i0 + rg;
        if (i < C) {
            const f32x4 v = __builtin_nontemporal_load(
                (const f32x4*)&ifeat[(size_t)(s0 + i) * DD + ct]);
            asum.x += v.x; asum.y += v.y; asum.z += v.z; asum.w += v.w;
            ushort4 h;
            h.x = f2bf(v.x); h.y = f2bf(v.y); h.z = f2bf(v.z); h.w = f2bf(v.w);
            *(ushort4*)&xbf[(size_t)(s0 + i) * DD + ct] = h;
        }
    }
    *(f32x4*)&ancp[rg][ct] = asum;
    __syncthreads();
    float a = ancp[0][t] + ancp[1][t] + ancp[2][t] + ancp[3][t];
    float m = a / fmaxf((float)C, 1.f);
    anc_s[t] = m;
    out[(size_t)b * 2 * DD + DD + t] = m;
    __syncthreads();
    // fused feat_v: coalesced wvT column-slab reads (L2-hot, 256KB)
    float fv = bv[t];
    #pragma unroll 4
    for (int k = 0; k < DD; k += 4) {
        fv += anc_s[k]     * wvT[(size_t)k * DD + t]
            + anc_s[k + 1] * wvT[(size_t)(k + 1) * DD + t]
            + anc_s[k + 2] * wvT[(size_t)(k + 2) * DD + t]
            + anc_s[k + 3] * wvT[(size_t)(k + 3) * DD + t];
    }
    feat_v[(size_t)b * DD + t] = fv;
}

// ---- K3: t[i] = exp( sigmoid(x_i@Wu^T + fv[seg_i]) . we ) --------------------
// 4 waves x 32 rows; A fragments from bf16 mirror (L3-hot) in registers;
// B tiles staged per-dt in LDS (double-buffered, shared by block); 1 barrier/dt.
__global__ __launch_bounds__(256, 3) void k_e(
    const unsigned short* __restrict__ xbf,
    const unsigned short* __restrict__ wub,
    const float* __restrict__ feat_v,
    const float* __restrict__ we,
    const int* __restrict__ seg,
    float* __restrict__ e_ws)
{
    __shared__ unsigned short bsh[2][4096];   // 2 x 8 KB dt-tiles of packed Wu
    const int t = threadIdx.x;
    const int w = t >> 6, lane = t & 63;
    const int colr = lane & 15, kg = lane >> 4;
    const int wbase = blockIdx.x * 128 + w * 32;

    // A fragments for this wave's 32 rows (row = wbase + rt*16 + colr)
    bf16x8 a[2][8];
    {
        const unsigned short* ap = &xbf[(size_t)(wbase + colr) * DD + kg * 8];
        #pragma unroll
        for (int rt = 0; rt < 2; ++rt)
            #pragma unroll
            for (int kt = 0; kt < 8; ++kt)
                a[rt][kt] = *(const bf16x8*)(ap + rt * 16 * DD + kt * 32);
    }

    int sgv[2][4];
    #pragma unroll
    for (int rt = 0; rt < 2; ++rt)
        #pragma unroll
        for (int r = 0; r < 4; ++r)
            sgv[rt][r] = seg[wbase + rt * 16 + kg * 4 + r];

    float epart[2][4];
    #pragma unroll
    for (int rt = 0; rt < 2; ++rt)
        #pragma unroll
        for (int r = 0; r < 4; ++r) epart[rt][r] = 0.f;

    // stage dt=0 tile (8 KB: 256 threads x 32 B, fully coalesced)
    {
        const uint4* s = (const uint4*)&wub[t * 16];
        uint4 v0 = s[0], v1 = s[1];
        *(uint4*)&bsh[0][t * 16] = v0;
        *(uint4*)&bsh[0][t * 16 + 8] = v1;
    }
    __syncthreads();

    #pragma unroll 2
    for (int dt = 0; dt < 16; ++dt) {
        const int cur = dt & 1;
        if (dt < 15) {   // prefetch next dt tile into the other buffer
            const uint4* s = (const uint4*)&wub[(dt + 1) * 4096 + t * 16];
            uint4 v0 = s[0], v1 = s[1];
            *(uint4*)&bsh[cur ^ 1][t * 16] = v0;
            *(uint4*)&bsh[cur ^ 1][t * 16 + 8] = v1;
        }

        f32x4 acc0 = (f32x4){0.f, 0.f, 0.f, 0.f};
        f32x4 acc1 = (f32x4){0.f, 0.f, 0.f, 0.f};
        #pragma unroll
        for (int kt = 0; kt < 8; ++kt) {
            bf16x8 bfr = *(const bf16x8*)&bsh[cur][kt * 512 + lane * 8];
            acc0 = __builtin_amdgcn_mfma_f32_16x16x32_bf16(a[0][kt], bfr, acc0, 0, 0, 0);
            acc1 = __builtin_amdgcn_mfma_f32_16x16x32_bf16(a[1][kt], bfr, acc1, 0, 0, 0);
        }

        const float wed = we[dt * 16 + colr];
        #pragma unroll
        for (int r = 0; r < 4; ++r) {
            float fv0 = feat_v[(size_t)sgv[0][r] * DD + dt * 16 + colr];
            float fv1 = feat_v[(size_t)sgv[1][r] * DD + dt * 16 + colr];
            float u0 = acc0[r] + fv0;
            float u1 = acc1[r] + fv1;
            epart[0][r] += wed * __builtin_amdgcn_rcpf(1.f + __expf(-u0));
            epart[1][r] += wed * __builtin_amdgcn_rcpf(1.f + __expf(-u1));
        }
        __syncthreads();
    }

    // reduce over the 16 colr lanes; store t = exp(e) (|e| <= sum|we| ~ 8,
    // so the softmax max-shift is unnecessary in f32)
    #pragma unroll
    for (int rt = 0; rt < 2; ++rt) {
        #pragma unroll
        for (int r = 0; r < 4; ++r) {
            float p = epart[rt][r];
            p += __shfl_xor(p, 1, 64);
            p += __shfl_xor(p, 2, 64);
            p += __shfl_xor(p, 4, 64);
            p += __shfl_xor(p, 8, 64);
            if (colr == 0) e_ws[wbase + rt * 16 + kg * 4 + r] = __expf(p);
        }
    }
}

// ---- K4: alpha = t/segsum(t); out[:,0:D] = sum alpha_i * x_i -----------------
__global__ __launch_bounds__(256) void k_rst(
    const unsigned short* __restrict__ xbf, const float* __restrict__ e_ws,
    const int* __restrict__ seg_start, float* __restrict__ out)
{
    int b = blockIdx.x, t = threadIdx.x;
    int s0 = seg_start[b], s1 = seg_start[b + 1];
    int C = s1 - s0;
    if (C <= 0) { out[(size_t)b * 2 * DD + t] = 0.f; return; }
    __shared__ float part[4][DD];
    __shared__ float red[4];
    __shared__ float bsum;
    int lane = t & 63, w = t >> 6;

    // denom = sum of t over the segment
    float s = 0.f;
    for (int i = t; i < C; i += 256) s += e_ws[s0 + i];
    #pragma unroll
    for (int off = 1; off < 64; off <<= 1) s += __shfl_xor(s, off, 64);
    if (lane == 0) red[w] = s;
    __syncthreads();
    if (t == 0) bsum = red[0] + red[1] + red[2] + red[3];
    __syncthreads();
    const float inv = 1.f / bsum;

    // weighted sum: 4 row-groups x 64 col-threads (ushort4 = 8B per lane)
    int rg = t >> 6, ct = (t & 63) * 4;
    f32x4 racc = {0.f, 0.f, 0.f, 0.f};
    for (int i0 = 0; i0 < C; i0 += 4) {
        int i = i0 + rg;
        if (i < C) {
            float al = e_ws[s0 + i];
            ushort4 v = *(const ushort4*)&xbf[(size_t)(s0 + i) * DD + ct];
            racc.x += al * bf2f(v.x);
            racc.y += al * bf2f(v.y);
            racc.z += al * bf2f(v.z);
            racc.w += al * bf2f(v.w);
        }
    }
    *(f32x4*)&part[rg][ct] = racc;
    __syncthreads();
    out[(size_t)b * 2 * DD + t] = (part[0][t] + part[1][t] + part[2][t] + part[3][t]) * inv;
}

extern "C" void kernel_launch(void* const* d_in, const int* in_sizes, int n_in,
                              void* d_out, int out_size, void* d_ws, size_t ws_size,
                              hipStream_t stream) {
    const float* ifeat = (const float*)d_in[0];
    const float* Wu    = (const float*)d_in[1];
    const float* Wv    = (const float*)d_in[2];
    const float* bv    = (const float*)d_in[3];
    const float* we    = (const float*)d_in[4];
    const int*   seg   = (const int*)d_in[5];
    float* out = (float*)d_out;

    char* ws = (char*)d_ws;
    int* seg_start        = (int*)ws;                                    // 32 KB pad
    unsigned short* wub   = (unsigned short*)(ws + 32768);               // 128 KB
    float* wvT            = (float*)(ws + 32768 + 131072);               // 256 KB
    float* feat_v         = (float*)(ws + 32768 + 131072 + 262144);      // 4 MB
    float* e_ws           = (float*)(ws + 32768 + 131072 + 262144 + 4194304); // 800 KB
    unsigned short* xbf   = (unsigned short*)(ws + 32768 + 131072 + 262144 + 4194304 + 819200); // 100 MB

    k_prep<<<dim3(337), dim3(256), 0, stream>>>(seg, Wu, Wv, seg_start, wub, wvT);
    k_anchor<<<dim3(SB), dim3(256), 0, stream>>>(ifeat, seg_start, wvT, bv, xbf, feat_v, out);
    k_e<<<dim3(NN / 128), dim3(256), 0, stream>>>(xbf, wub, feat_v, we, seg, e_ws);
    k_rst<<<dim3(SB), dim3(256), 0, stream>>>(xbf, e_ws, seg_start, out);
}

// Round 16
// 153.368 us; speedup vs baseline: 1.0901x; 1.0901x over previous
//
#include <hip/hip_runtime.h>
#include <hip/hip_bf16.h>

#define DD 256
#define NN 204800
#define SB 4096

typedef __attribute__((ext_vector_type(8))) short bf16x8;
typedef __attribute__((ext_vector_type(4))) float f32x4;

__device__ __forceinline__ unsigned short f2bf(float x) {
    union { float f; unsigned u; } v; v.f = x;
    unsigned r = v.u + 0x7FFF + ((v.u >> 16) & 1);
    return (unsigned short)(r >> 16);
}
__device__ __forceinline__ float bf2f(unsigned short h) {
    union { unsigned u; float f; } v; v.u = ((unsigned)h) << 16;
    return v.f;
}

// ---- K1: segstart (blocks 0..16) + pack Wu -> bf16 fragment order (17..272) --
// pack: o = ((dt*8+kt)*64 + kg*16 + colr)*8 + j <- Wu[(dt*16+colr)][kt*32+kg*8+j]
__global__ void k_prep(const int* __restrict__ seg, const float* __restrict__ Wu,
                       int* __restrict__ seg_start, unsigned short* __restrict__ wub) {
    int blk = blockIdx.x, t = threadIdx.x;
    if (blk < 17) {
        int b = blk * 256 + t;
        if (b > SB) return;
        int lo = 0, hi = NN;
        while (lo < hi) {
            int mid = (lo + hi) >> 1;
            if (seg[mid] < b) lo = mid + 1; else hi = mid;
        }
        seg_start[b] = lo;
    } else {
        int o = (blk - 17) * 256 + t;        // 65536 total
        int j    = o & 7;
        int colr = (o >> 3) & 15;
        int kg   = (o >> 7) & 3;
        int kt   = (o >> 9) & 7;
        int dt   = o >> 12;
        wub[o] = f2bf(Wu[(dt * 16 + colr) * DD + kt * 32 + kg * 8 + j]);
    }
}

// ---- K2: anchor = segment mean (f32) + write bf16 copy of ifeat --------------
// ifeat is read exactly once across the whole pipeline -> nontemporal loads,
// so the 210MB f32 stream doesn't evict the 105MB bf16 mirror from L3.
__global__ __launch_bounds__(256) void k_anchor(
    const float* __restrict__ ifeat, const int* __restrict__ seg_start,
    unsigned short* __restrict__ xbf, float* __restrict__ anc_ws,
    float* __restrict__ out)
{
    __shared__ float ancp[4][DD];
    int b = blockIdx.x, t = threadIdx.x;
    int rg = t >> 6, ct = (t & 63) * 4;
    int s0 = seg_start[b], s1 = seg_start[b + 1];
    int C = s1 - s0;
    f32x4 asum = {0.f, 0.f, 0.f, 0.f};
    for (int i0 = 0; i0 < C; i0 += 4) {
        int i = i0 + rg;
        if (i < C) {
            const f32x4 v = __builtin_nontemporal_load(
                (const f32x4*)&ifeat[(size_t)(s0 + i) * DD + ct]);
            asum.x += v.x; asum.y += v.y; asum.z += v.z; asum.w += v.w;
            ushort4 h;
            h.x = f2bf(v.x); h.y = f2bf(v.y); h.z = f2bf(v.z); h.w = f2bf(v.w);
            *(ushort4*)&xbf[(size_t)(s0 + i) * DD + ct] = h;
        }
    }
    *(f32x4*)&ancp[rg][ct] = asum;
    __syncthreads();
    float a = ancp[0][t] + ancp[1][t] + ancp[2][t] + ancp[3][t];
    float m = a / fmaxf((float)C, 1.f);
    anc_ws[b * DD + t] = m;
    out[(size_t)b * 2 * DD + DD + t] = m;
}

// ---- K3: feat_v = anchor @ Wv^T + bv  (16 segments per block) ----------------
__global__ void k_featv(const float* __restrict__ anc_ws, const float* __restrict__ Wv,
                        const float* __restrict__ bv, float* __restrict__ feat_v) {
    int b0 = blockIdx.x * 16;
    int d = threadIdx.x;
    __shared__ float anc[16][DD];
    #pragma unroll
    for (int r = 0; r < 16; ++r) anc[r][d] = anc_ws[(b0 + r) * DD + d];
    __syncthreads();
    float acc[16];
    float bvd = bv[d];
    #pragma unroll
    for (int r = 0; r < 16; ++r) acc[r] = bvd;
    for (int k = 0; k < DD; k += 4) {
        float4 wv4 = *(const float4*)&Wv[d * DD + k];
        #pragma unroll
        for (int r = 0; r < 16; ++r) {
            acc[r] += wv4.x * anc[r][k] + wv4.y * anc[r][k + 1]
                    + wv4.z * anc[r][k + 2] + wv4.w * anc[r][k + 3];
        }
    }
    #pragma unroll
    for (int r = 0; r < 16; ++r) feat_v[(b0 + r) * DD + d] = acc[r];
}

// ---- K4: t[i] = exp( sigmoid(x_i@Wu^T + fv[seg_i]) . we ) --------------------
// 4 waves x 32 rows; A fragments from bf16 mirror (L3-hot) in registers;
// B tiles staged per-dt in LDS (double-buffered, shared by block); 1 barrier/dt.
__global__ __launch_bounds__(256, 3) void k_e(
    const unsigned short* __restrict__ xbf,
    const unsigned short* __restrict__ wub,
    const float* __restrict__ feat_v,
    const float* __restrict__ we,
    const int* __restrict__ seg,
    float* __restrict__ e_ws)
{
    __shared__ unsigned short bsh[2][4096];   // 2 x 8 KB dt-tiles of packed Wu
    const int t = threadIdx.x;
    const int w = t >> 6, lane = t & 63;
    const int colr = lane & 15, kg = lane >> 4;
    const int wbase = blockIdx.x * 128 + w * 32;

    // A fragments for this wave's 32 rows (row = wbase + rt*16 + colr)
    bf16x8 a[2][8];
    {
        const unsigned short* ap = &xbf[(size_t)(wbase + colr) * DD + kg * 8];
        #pragma unroll
        for (int rt = 0; rt < 2; ++rt)
            #pragma unroll
            for (int kt = 0; kt < 8; ++kt)
                a[rt][kt] = *(const bf16x8*)(ap + rt * 16 * DD + kt * 32);
    }

    int sgv[2][4];
    #pragma unroll
    for (int rt = 0; rt < 2; ++rt)
        #pragma unroll
        for (int r = 0; r < 4; ++r)
            sgv[rt][r] = seg[wbase + rt * 16 + kg * 4 + r];

    float epart[2][4];
    #pragma unroll
    for (int rt = 0; rt < 2; ++rt)
        #pragma unroll
        for (int r = 0; r < 4; ++r) epart[rt][r] = 0.f;

    // stage dt=0 tile (8 KB: 256 threads x 32 B, fully coalesced)
    {
        const uint4* s = (const uint4*)&wub[t * 16];
        uint4 v0 = s[0], v1 = s[1];
        *(uint4*)&bsh[0][t * 16] = v0;
        *(uint4*)&bsh[0][t * 16 + 8] = v1;
    }
    __syncthreads();

    #pragma unroll 2
    for (int dt = 0; dt < 16; ++dt) {
        const int cur = dt & 1;
        if (dt < 15) {   // prefetch next dt tile into the other buffer
            const uint4* s = (const uint4*)&wub[(dt + 1) * 4096 + t * 16];
            uint4 v0 = s[0], v1 = s[1];
            *(uint4*)&bsh[cur ^ 1][t * 16] = v0;
            *(uint4*)&bsh[cur ^ 1][t * 16 + 8] = v1;
        }

        f32x4 acc0 = (f32x4){0.f, 0.f, 0.f, 0.f};
        f32x4 acc1 = (f32x4){0.f, 0.f, 0.f, 0.f};
        #pragma unroll
        for (int kt = 0; kt < 8; ++kt) {
            bf16x8 bfr = *(const bf16x8*)&bsh[cur][kt * 512 + lane * 8];
            acc0 = __builtin_amdgcn_mfma_f32_16x16x32_bf16(a[0][kt], bfr, acc0, 0, 0, 0);
            acc1 = __builtin_amdgcn_mfma_f32_16x16x32_bf16(a[1][kt], bfr, acc1, 0, 0, 0);
        }

        const float wed = we[dt * 16 + colr];
        #pragma unroll
        for (int r = 0; r < 4; ++r) {
            float fv0 = feat_v[(size_t)sgv[0][r] * DD + dt * 16 + colr];
            float fv1 = feat_v[(size_t)sgv[1][r] * DD + dt * 16 + colr];
            float u0 = acc0[r] + fv0;
            float u1 = acc1[r] + fv1;
            epart[0][r] += wed * __builtin_amdgcn_rcpf(1.f + __expf(-u0));
            epart[1][r] += wed * __builtin_amdgcn_rcpf(1.f + __expf(-u1));
        }
        __syncthreads();
    }

    // reduce over the 16 colr lanes; store t = exp(e) (|e| <= sum|we| ~ 8,
    // so the softmax max-shift is unnecessary in f32)
    #pragma unroll
    for (int rt = 0; rt < 2; ++rt) {
        #pragma unroll
        for (int r = 0; r < 4; ++r) {
            float p = epart[rt][r];
            p += __shfl_xor(p, 1, 64);
            p += __shfl_xor(p, 2, 64);
            p += __shfl_xor(p, 4, 64);
            p += __shfl_xor(p, 8, 64);
            if (colr == 0) e_ws[wbase + rt * 16 + kg * 4 + r] = __expf(p);
        }
    }
}

// ---- K5: alpha = t/segsum(t); out[:,0:D] = sum alpha_i * x_i -----------------
__global__ __launch_bounds__(256) void k_rst(
    const unsigned short* __restrict__ xbf, const float* __restrict__ e_ws,
    const int* __restrict__ seg_start, float* __restrict__ out)
{
    int b = blockIdx.x, t = threadIdx.x;
    int s0 = seg_start[b], s1 = seg_start[b + 1];
    int C = s1 - s0;
    if (C <= 0) { out[(size_t)b * 2 * DD + t] = 0.f; return; }
    __shared__ float part[4][DD];
    __shared__ float red[4];
    __shared__ float bsum;
    int lane = t & 63, w = t >> 6;

    // denom = sum of t over the segment
    float s = 0.f;
    for (int i = t; i < C; i += 256) s += e_ws[s0 + i];
    #pragma unroll
    for (int off = 1; off < 64; off <<= 1) s += __shfl_xor(s, off, 64);
    if (lane == 0) red[w] = s;
    __syncthreads();
    if (t == 0) bsum = red[0] + red[1] + red[2] + red[3];
    __syncthreads();
    const float inv = 1.f / bsum;

    // weighted sum: 4 row-groups x 64 col-threads (ushort4 = 8B per lane)
    int rg = t >> 6, ct = (t & 63) * 4;
    f32x4 racc = {0.f, 0.f, 0.f, 0.f};
    for (int i0 = 0; i0 < C; i0 += 4) {
        int i = i0 + rg;
        if (i < C) {
            float al = e_ws[s0 + i];
            ushort4 v = *(const ushort4*)&xbf[(size_t)(s0 + i) * DD + ct];
            racc.x += al * bf2f(v.x);
            racc.y += al * bf2f(v.y);
            racc.z += al * bf2f(v.z);
            racc.w += al * bf2f(v.w);
        }
    }
    *(f32x4*)&part[rg][ct] = racc;
    __syncthreads();
    out[(size_t)b * 2 * DD + t] = (part[0][t] + part[1][t] + part[2][t] + part[3][t]) * inv;
}

extern "C" void kernel_launch(void* const* d_in, const int* in_sizes, int n_in,
                              void* d_out, int out_size, void* d_ws, size_t ws_size,
                              hipStream_t stream) {
    const float* ifeat = (const float*)d_in[0];
    const float* Wu    = (const float*)d_in[1];
    const float* Wv    = (const float*)d_in[2];
    const float* bv    = (const float*)d_in[3];
    const float* we    = (const float*)d_in[4];
    const int*   seg   = (const int*)d_in[5];
    float* out = (float*)d_out;

    char* ws = (char*)d_ws;
    int* seg_start        = (int*)ws;                                    // 32 KB pad
    unsigned short* wub   = (unsigned short*)(ws + 32768);               // 128 KB
    float* anc_ws         = (float*)(ws + 32768 + 131072);               // 4 MB
    float* feat_v         = (float*)(ws + 32768 + 131072 + 4194304);     // 4 MB
    float* e_ws           = (float*)(ws + 32768 + 131072 + 8388608);     // 800 KB
    unsigned short* xbf   = (unsigned short*)(ws + 32768 + 131072 + 8388608 + 819200); // 100 MB

    k_prep<<<dim3(273), dim3(256), 0, stream>>>(seg, Wu, seg_start, wub);
    k_anchor<<<dim3(SB), dim3(256), 0, stream>>>(ifeat, seg_start, xbf, anc_ws, out);
    k_featv<<<dim3(SB / 16), dim3(256), 0, stream>>>(anc_ws, Wv, bv, feat_v);
    k_e<<<dim3(NN / 128), dim3(256), 0, stream>>>(xbf, wub, feat_v, we, seg, e_ws);
    k_rst<<<dim3(SB), dim3(256), 0, stream>>>(xbf, e_ws, seg_start, out);
}